// Round 1
// baseline (16388.762 us; speedup 1.0000x reference)
//
#include <hip/hip_runtime.h>
#include <hip/hip_bf16.h>
#include <cstdint>
#include <cstring>

#define T_DIM 2048
#define B_DIM 64
#define H_DIM 256

// ---------------- ws layout ----------------
// [0, 201326592)            gi bf16  (T*B*768)
// [201326592, +393216)      packed recurrent weights: uint32 whp[k2*768 + c],
//                           bf16x2 of (W[2k2][c], W[2k2+1][c]); c: 0..255=Whr, 256..511=Whz, 512..767=Whn
// [201719808, +131072)      canonical resets u8
// [201850880, +4)           resets dtype flag (0=i32, 1=u8, 2=f32)
static const size_t WS_GI   = 0;
static const size_t WS_WHP  = 201326592;
static const size_t WS_RST  = WS_WHP + 393216;
static const size_t WS_FLAG = WS_RST + 131072;

static __device__ __forceinline__ float bflo(uint32_t w) {
  uint32_t v = w << 16; float f; memcpy(&f, &v, 4); return f;
}
static __device__ __forceinline__ float bfhi(uint32_t w) {
  uint32_t v = w & 0xFFFF0000u; float f; memcpy(&f, &v, 4); return f;
}

// ---------------- resets dtype detection ----------------
// resets is (T,B)=131072 bools; harness may hand it to us as u8, i32, or f32.
// Scan first 32768 words (128KB — safe under every candidate encoding):
//   f32 encoding -> some words are exactly 0x3F800000 (1.0f)
//   u8  encoding -> words composed of 0x00/0x01 bytes, many > 1
//   i32 encoding -> words are only 0 or 1 (no votes)
__global__ __launch_bounds__(256) void detect_resets(const uint32_t* __restrict__ rbuf,
                                                     int* __restrict__ flag_out) {
  __shared__ int v_u8, v_f32;
  if (threadIdx.x == 0) { v_u8 = 0; v_f32 = 0; }
  __syncthreads();
  int cu = 0, cf = 0;
  for (int i = threadIdx.x; i < 32768; i += 256) {
    uint32_t w = rbuf[i];
    if (w == 0x3F800000u) cf++;
    else if (w > 1u && (w & 0xFEFEFEFEu) == 0u) cu++;
  }
  atomicAdd(&v_u8, cu);
  atomicAdd(&v_f32, cf);
  __syncthreads();
  if (threadIdx.x == 0) *flag_out = (v_f32 > 0) ? 2 : ((v_u8 > 0) ? 1 : 0);
}

__global__ __launch_bounds__(256) void expand_resets(const void* __restrict__ rbuf,
                                                     const int* __restrict__ flag,
                                                     uint8_t* __restrict__ out) {
  int i = blockIdx.x * 256 + threadIdx.x;
  if (i >= T_DIM * B_DIM) return;
  int f = *flag;
  uint8_t v;
  if (f == 1)      v = (((const uint8_t*)rbuf)[i] != 0);
  else if (f == 2) v = (((const float*)rbuf)[i] != 0.f);
  else             v = (((const int*)rbuf)[i] != 0);
  out[i] = v;
}

// ---------------- recurrent weight pack (f32 -> bf16x2 along K) ----------------
__global__ __launch_bounds__(256) void pack_weights(const float* __restrict__ Whr,
                                                    const float* __restrict__ Whz,
                                                    const float* __restrict__ Whn,
                                                    uint32_t* __restrict__ whp) {
  int idx = blockIdx.x * 256 + threadIdx.x;
  if (idx >= 128 * 768) return;
  int c = idx % 768, k2 = idx / 768;
  const float* W = (c < 256) ? Whr : ((c < 512) ? Whz : Whn);
  int cc = c & 255;
  float lo = W[(size_t)(2 * k2) * 256 + cc];
  float hi = W[(size_t)(2 * k2 + 1) * 256 + cc];
  __hip_bfloat16 bl = __float2bfloat16(lo), bh = __float2bfloat16(hi);
  uint16_t ul, uh; memcpy(&ul, &bl, 2); memcpy(&uh, &bh, 2);
  whp[idx] = (uint32_t)ul | ((uint32_t)uh << 16);
}

// ---------------- gi = x @ Wi + bi (f32 compute, bf16 store) ----------------
// Block: 16 rows of (T*B) x 768 cols; 256 threads, thread j owns cols {j, 256+j, 512+j}.
__global__ __launch_bounds__(256) void gi_gemm(const float* __restrict__ x,
                                               const float* __restrict__ Wi,
                                               const float* __restrict__ bi,
                                               __hip_bfloat16* __restrict__ gi) {
  __shared__ float xs[16 * 256];  // transposed: xs[k*16 + r]
  const size_t m0 = (size_t)blockIdx.x * 16;
  for (int idx = threadIdx.x; idx < 4096; idx += 256) {
    int r = idx >> 8, k = idx & 255;
    xs[k * 16 + r] = x[m0 * 256 + idx];
  }
  __syncthreads();
  const int j = threadIdx.x;
  float acc0[16], acc1[16], acc2[16];
#pragma unroll
  for (int r = 0; r < 16; ++r) { acc0[r] = 0.f; acc1[r] = 0.f; acc2[r] = 0.f; }
  for (int k = 0; k < 256; ++k) {
    float w0 = Wi[(size_t)k * 768 + j];
    float w1 = Wi[(size_t)k * 768 + 256 + j];
    float w2 = Wi[(size_t)k * 768 + 512 + j];
    const float* xk = &xs[k * 16];
#pragma unroll
    for (int r = 0; r < 16; ++r) {
      float xv = xk[r];
      acc0[r] = fmaf(xv, w0, acc0[r]);
      acc1[r] = fmaf(xv, w1, acc1[r]);
      acc2[r] = fmaf(xv, w2, acc2[r]);
    }
  }
  float b0 = bi[j], b1 = bi[256 + j], b2 = bi[512 + j];
#pragma unroll
  for (int r = 0; r < 16; ++r) {
    size_t base = (m0 + r) * 768;
    gi[base + j]       = __float2bfloat16(acc0[r] + b0);
    gi[base + 256 + j] = __float2bfloat16(acc1[r] + b1);
    gi[base + 512 + j] = __float2bfloat16(acc2[r] + b2);
  }
}

// ---------------- GRU recurrence ----------------
// One workgroup per batch row b; thread j owns output column j of h.
// h lives in LDS; weights streamed as packed bf16x2; f32 accumulate.
// Reset masking: sums are linear in h, so apply mask to the sums + carry term.
__global__ __launch_bounds__(256) void gru_rec(const __hip_bfloat16* __restrict__ gi,
                                               const uint8_t* __restrict__ rst,
                                               const float* __restrict__ h0,
                                               const uint32_t* __restrict__ whp,
                                               const float* __restrict__ bhn,
                                               float* __restrict__ out) {
  __shared__ float hs[256];
  const int b = blockIdx.x, j = threadIdx.x;
  hs[j] = h0[b * 256 + j];
  const float bn = bhn[j];
  __syncthreads();
  const float2* h2 = reinterpret_cast<const float2*>(hs);
  for (int t = 0; t < 2048; ++t) {
    const float m = rst[t * 64 + b] ? 0.f : 1.f;
    float sr = 0.f, sz = 0.f, sn = 0.f;
#pragma unroll 4
    for (int k2 = 0; k2 < 128; ++k2) {
      float2 hp = h2[k2];
      uint32_t w0 = whp[k2 * 768 + j];
      uint32_t w1 = whp[k2 * 768 + 256 + j];
      uint32_t w2 = whp[k2 * 768 + 512 + j];
      sr = fmaf(hp.x, bflo(w0), sr); sr = fmaf(hp.y, bfhi(w0), sr);
      sz = fmaf(hp.x, bflo(w1), sz); sz = fmaf(hp.y, bfhi(w1), sz);
      sn = fmaf(hp.x, bflo(w2), sn); sn = fmaf(hp.y, bfhi(w2), sn);
    }
    const float hj = m * hs[j];
    const size_t gb = ((size_t)t * 64 + b) * 768;
    float gr = __bfloat162float(gi[gb + j]);
    float gz = __bfloat162float(gi[gb + 256 + j]);
    float gn = __bfloat162float(gi[gb + 512 + j]);
    float r = 1.f / (1.f + __expf(-(gr + m * sr)));
    float z = 1.f / (1.f + __expf(-(gz + m * sz)));
    float n = tanhf(gn + r * (m * sn + bn));
    float hn = (1.f - z) * n + z * hj;
    out[16384 + ((size_t)t * 64 + b) * 256 + j] = hn;
    __syncthreads();
    hs[j] = hn;
    __syncthreads();
  }
  out[b * 256 + j] = hs[j];
}

extern "C" void kernel_launch(void* const* d_in, const int* in_sizes, int n_in,
                              void* d_out, int out_size, void* d_ws, size_t ws_size,
                              hipStream_t stream) {
  const float* x   = (const float*)d_in[0];
  const void*  rin = d_in[1];
  const float* h0  = (const float*)d_in[2];
  const float* Wi  = (const float*)d_in[3];
  const float* bi  = (const float*)d_in[4];
  const float* Whr = (const float*)d_in[5];
  const float* Whz = (const float*)d_in[6];
  const float* Whn = (const float*)d_in[7];
  const float* bhn = (const float*)d_in[8];
  float* out = (float*)d_out;

  char* ws = (char*)d_ws;
  __hip_bfloat16* gi = (__hip_bfloat16*)(ws + WS_GI);
  uint32_t* whp      = (uint32_t*)(ws + WS_WHP);
  uint8_t* rst       = (uint8_t*)(ws + WS_RST);
  int* flag          = (int*)(ws + WS_FLAG);

  hipLaunchKernelGGL(detect_resets, dim3(1), dim3(256), 0, stream,
                     (const uint32_t*)rin, flag);
  hipLaunchKernelGGL(expand_resets, dim3(512), dim3(256), 0, stream, rin, flag, rst);
  hipLaunchKernelGGL(pack_weights, dim3(384), dim3(256), 0, stream, Whr, Whz, Whn, whp);
  hipLaunchKernelGGL(gi_gemm, dim3(8192), dim3(256), 0, stream, x, Wi, bi, gi);
  hipLaunchKernelGGL(gru_rec, dim3(64), dim3(256), 0, stream, gi, rst, h0, whp, bhn, out);
}

// Round 2
// 7739.671 us; speedup vs baseline: 2.1175x; 2.1175x over previous
//
#include <hip/hip_runtime.h>
#include <hip/hip_bf16.h>
#include <cstdint>
#include <cstring>

#define T_DIM 2048
#define B_DIM 64
#define H_DIM 256

typedef __attribute__((ext_vector_type(8))) short bf16x8;
typedef __attribute__((ext_vector_type(4))) float f32x4;
typedef __attribute__((ext_vector_type(4))) short short4v;

// ---------------- ws layout ----------------
// [0, 201326592)            gi bf16  (T*B*768)
// [201326592, +131072)      canonical resets u8
// [+4]                      resets dtype flag
static const size_t WS_GI   = 0;
static const size_t WS_RST  = 201326592;
static const size_t WS_FLAG = WS_RST + 131072;

static __device__ __forceinline__ short f2bs(float f) {
  __hip_bfloat16 b = __float2bfloat16(f);
  short s; memcpy(&s, &b, 2); return s;
}
static __device__ __forceinline__ float bs2f(unsigned short u) {
  uint32_t v = ((uint32_t)u) << 16; float f; memcpy(&f, &v, 4); return f;
}
static __device__ __forceinline__ float sigm(float x) {
  return 1.f / (1.f + __expf(-x));
}
static __device__ __forceinline__ float tanh_fast(float x) {
  return 1.f - 2.f / (__expf(2.f * x) + 1.f);
}

// ---------------- resets dtype detection (unchanged, passed R1) ----------------
__global__ __launch_bounds__(256) void detect_resets(const uint32_t* __restrict__ rbuf,
                                                     int* __restrict__ flag_out) {
  __shared__ int v_u8, v_f32;
  if (threadIdx.x == 0) { v_u8 = 0; v_f32 = 0; }
  __syncthreads();
  int cu = 0, cf = 0;
  for (int i = threadIdx.x; i < 32768; i += 256) {
    uint32_t w = rbuf[i];
    if (w == 0x3F800000u) cf++;
    else if (w > 1u && (w & 0xFEFEFEFEu) == 0u) cu++;
  }
  atomicAdd(&v_u8, cu);
  atomicAdd(&v_f32, cf);
  __syncthreads();
  if (threadIdx.x == 0) *flag_out = (v_f32 > 0) ? 2 : ((v_u8 > 0) ? 1 : 0);
}

__global__ __launch_bounds__(256) void expand_resets(const void* __restrict__ rbuf,
                                                     const int* __restrict__ flag,
                                                     uint8_t* __restrict__ out) {
  int i = blockIdx.x * 256 + threadIdx.x;
  if (i >= T_DIM * B_DIM) return;
  int f = *flag;
  uint8_t v;
  if (f == 1)      v = (((const uint8_t*)rbuf)[i] != 0);
  else if (f == 2) v = (((const float*)rbuf)[i] != 0.f);
  else             v = (((const int*)rbuf)[i] != 0);
  out[i] = v;
}

// ---------------- gi = x @ Wi + bi via MFMA (bf16 inputs, f32 acc) ----------------
// 256 wgs x 1024 thr (16 waves). Wave w owns output cols [w*48, w*48+48).
// Wi fragments resident in VGPRs; per 16-row tile: stage x (f32->bf16) into
// LDS A-fragment layout, MFMA, scatter-store bf16 gi per C layout.
// A-frag LDS layout: blk = k>>3 (0..31), idx = blk*136 + row*8 + (k&7)  [pad 8 shorts/blk]
__global__ __launch_bounds__(1024) void gi_gemm_mfma(const float* __restrict__ x,
                                                     const float* __restrict__ Wi,
                                                     const float* __restrict__ bi,
                                                     __hip_bfloat16* __restrict__ gi_) {
  __shared__ short hfrag[32 * 136];
  const int tid = threadIdx.x;
  const int lane = tid & 63, wave = tid >> 6;
  const int lq = lane >> 4, l15 = lane & 15;
  unsigned short* gi16 = (unsigned short*)gi_;

  // resident Wi fragments: B[k][n], lane holds k = ks*32 + lq*8 + e, n = colb + nt*16
  bf16x8 wfrag[3][8];
  const int colb = wave * 48 + l15;
#pragma unroll
  for (int nt = 0; nt < 3; ++nt) {
#pragma unroll
    for (int ks = 0; ks < 8; ++ks) {
      bf16x8 f;
#pragma unroll
      for (int e = 0; e < 8; ++e)
        f[e] = f2bs(Wi[(size_t)(ks * 32 + lq * 8 + e) * 768 + colb + nt * 16]);
      wfrag[nt][ks] = f;
    }
  }
  const float b0 = bi[colb], b1 = bi[colb + 16], b2 = bi[colb + 32];

  const int r = wave;            // staging: row ownership
  const int kc = (tid & 63) * 4; // staging: k-chunk ownership
  const size_t m0 = (size_t)blockIdx.x * 32 * 16;

  float4 xv = *(const float4*)&x[(m0 + r) * 256 + kc];
  for (int i = 0; i < 32; ++i) {
    short4v xb = { f2bs(xv.x), f2bs(xv.y), f2bs(xv.z), f2bs(xv.w) };
    *(short4v*)&hfrag[(kc >> 3) * 136 + r * 8 + (kc & 7)] = xb;
    __syncthreads();
    if (i + 1 < 32)
      xv = *(const float4*)&x[(m0 + (size_t)(i + 1) * 16 + r) * 256 + kc];
    f32x4 c0 = {0.f,0.f,0.f,0.f}, c1 = {0.f,0.f,0.f,0.f}, c2 = {0.f,0.f,0.f,0.f};
#pragma unroll
    for (int ks = 0; ks < 8; ++ks) {
      bf16x8 a = *(const bf16x8*)&hfrag[(ks * 4 + lq) * 136 + l15 * 8];
      c0 = __builtin_amdgcn_mfma_f32_16x16x32_bf16(a, wfrag[0][ks], c0, 0, 0, 0);
      c1 = __builtin_amdgcn_mfma_f32_16x16x32_bf16(a, wfrag[1][ks], c1, 0, 0, 0);
      c2 = __builtin_amdgcn_mfma_f32_16x16x32_bf16(a, wfrag[2][ks], c2, 0, 0, 0);
    }
    __syncthreads();
    const size_t rowb = m0 + (size_t)i * 16;
#pragma unroll
    for (int qq = 0; qq < 4; ++qq) {
      const size_t row = rowb + lq * 4 + qq;   // C/D: row = (lane>>4)*4 + reg
      gi16[row * 768 + colb]      = (unsigned short)f2bs(c0[qq] + b0);
      gi16[row * 768 + colb + 16] = (unsigned short)f2bs(c1[qq] + b1);
      gi16[row * 768 + colb + 32] = (unsigned short)f2bs(c2[qq] + b2);
    }
  }
}

// ---------------- GRU recurrence via MFMA, weights resident in VGPRs ----------------
// 4 wgs x 1024 thr; wg owns batch rows [bg, bg+16). Per step:
//   [A-read from LDS + 24 MFMA/wave + S scatter to LDS] B1 [pointwise] B2
// h carried in f32 registers per-thread; LDS hfrag (bf16 A-layout) feeds MFMA.
__global__ __launch_bounds__(1024) void gru_rec_mfma(const __hip_bfloat16* __restrict__ gi_,
                                                     const uint8_t* __restrict__ rst,
                                                     const float* __restrict__ h0,
                                                     const float* __restrict__ Whr,
                                                     const float* __restrict__ Whz,
                                                     const float* __restrict__ Whn,
                                                     const float* __restrict__ bhn,
                                                     float* __restrict__ out) {
  __shared__ short hfrag[32 * 136];  // padded A-frag layout, 8.5KB
  __shared__ float S[16 * 768];      // gate pre-activations, 48KB
  const int tid = threadIdx.x;
  const int lane = tid & 63, wave = tid >> 6;
  const int lq = lane >> 4, l15 = lane & 15;
  const int bg = blockIdx.x * 16;
  const unsigned short* gi16 = (const unsigned short*)gi_;

  // resident recurrent-weight fragments (cols: 0..255=Whr, 256..511=Whz, 512..767=Whn)
  bf16x8 wfrag[3][8];
#pragma unroll
  for (int nt = 0; nt < 3; ++nt) {
    const int n0 = wave * 48 + nt * 16;                 // tile never straddles a matrix
    const float* W = (n0 < 256) ? Whr : ((n0 < 512) ? Whz : Whn);
    const int cc = (n0 & 255) + l15;
#pragma unroll
    for (int ks = 0; ks < 8; ++ks) {
      bf16x8 f;
#pragma unroll
      for (int e = 0; e < 8; ++e)
        f[e] = f2bs(W[(size_t)(ks * 32 + lq * 8 + e) * 256 + cc]);
      wfrag[nt][ks] = f;
    }
  }

  // pointwise ownership: row r = wave, k-chunk kc (4 consecutive)
  const int r = wave;
  const int kc = (tid & 63) * 4;
  float hreg[4];
  {
    const float4 h0v = *(const float4*)&h0[(size_t)(bg + r) * 256 + kc];
    hreg[0] = h0v.x; hreg[1] = h0v.y; hreg[2] = h0v.z; hreg[3] = h0v.w;
    short4v hb = { f2bs(hreg[0]), f2bs(hreg[1]), f2bs(hreg[2]), f2bs(hreg[3]) };
    *(short4v*)&hfrag[(kc >> 3) * 136 + r * 8 + (kc & 7)] = hb;
  }
  const float bnv[4] = { bhn[kc], bhn[kc + 1], bhn[kc + 2], bhn[kc + 3] };
  const int colb = wave * 48 + l15;
  __syncthreads();

  for (int t = 0; t < 2048; ++t) {
    // prefetch gi + reset for this step (consumed after MFMA phase)
    const size_t gb = ((size_t)t * 64 + bg + r) * 768 + kc;
    const ushort4 g0 = *(const ushort4*)&gi16[gb];
    const ushort4 g1 = *(const ushort4*)&gi16[gb + 256];
    const ushort4 g2 = *(const ushort4*)&gi16[gb + 512];
    const uint8_t rs = rst[t * 64 + bg + r];

    // S = h @ [Whr|Whz|Whn]
    f32x4 c0 = {0.f,0.f,0.f,0.f}, c1 = {0.f,0.f,0.f,0.f}, c2 = {0.f,0.f,0.f,0.f};
#pragma unroll
    for (int ks = 0; ks < 8; ++ks) {
      bf16x8 a = *(const bf16x8*)&hfrag[(ks * 4 + lq) * 136 + l15 * 8];
      c0 = __builtin_amdgcn_mfma_f32_16x16x32_bf16(a, wfrag[0][ks], c0, 0, 0, 0);
      c1 = __builtin_amdgcn_mfma_f32_16x16x32_bf16(a, wfrag[1][ks], c1, 0, 0, 0);
      c2 = __builtin_amdgcn_mfma_f32_16x16x32_bf16(a, wfrag[2][ks], c2, 0, 0, 0);
    }
#pragma unroll
    for (int qq = 0; qq < 4; ++qq) {
      const int row = lq * 4 + qq;
      S[row * 768 + colb]      = c0[qq];
      S[row * 768 + colb + 16] = c1[qq];
      S[row * 768 + colb + 32] = c2[qq];
    }
    __syncthreads();

    // pointwise: masks are linear-safe (sums linear in h)
    const float m = rs ? 0.f : 1.f;
    const float4 sr = *(const float4*)&S[r * 768 + kc];
    const float4 sz = *(const float4*)&S[r * 768 + 256 + kc];
    const float4 sn = *(const float4*)&S[r * 768 + 512 + kc];
    const float srv[4] = { sr.x, sr.y, sr.z, sr.w };
    const float szv[4] = { sz.x, sz.y, sz.z, sz.w };
    const float snv[4] = { sn.x, sn.y, sn.z, sn.w };
    const float grv[4] = { bs2f(g0.x), bs2f(g0.y), bs2f(g0.z), bs2f(g0.w) };
    const float gzv[4] = { bs2f(g1.x), bs2f(g1.y), bs2f(g1.z), bs2f(g1.w) };
    const float gnv[4] = { bs2f(g2.x), bs2f(g2.y), bs2f(g2.z), bs2f(g2.w) };
#pragma unroll
    for (int jj = 0; jj < 4; ++jj) {
      const float rr = sigm(grv[jj] + m * srv[jj]);
      const float zz = sigm(gzv[jj] + m * szv[jj]);
      const float nn = tanh_fast(gnv[jj] + rr * (m * snv[jj] + bnv[jj]));
      hreg[jj] = (1.f - zz) * nn + zz * (m * hreg[jj]);
    }
    const short4v hb = { f2bs(hreg[0]), f2bs(hreg[1]), f2bs(hreg[2]), f2bs(hreg[3]) };
    *(short4v*)&hfrag[(kc >> 3) * 136 + r * 8 + (kc & 7)] = hb;
    float4 ho; ho.x = hreg[0]; ho.y = hreg[1]; ho.z = hreg[2]; ho.w = hreg[3];
    *(float4*)&out[16384 + ((size_t)t * 64 + bg + r) * 256 + kc] = ho;
    __syncthreads();
  }

  float4 hf; hf.x = hreg[0]; hf.y = hreg[1]; hf.z = hreg[2]; hf.w = hreg[3];
  *(float4*)&out[(size_t)(bg + r) * 256 + kc] = hf;
}

extern "C" void kernel_launch(void* const* d_in, const int* in_sizes, int n_in,
                              void* d_out, int out_size, void* d_ws, size_t ws_size,
                              hipStream_t stream) {
  const float* x   = (const float*)d_in[0];
  const void*  rin = d_in[1];
  const float* h0  = (const float*)d_in[2];
  const float* Wi  = (const float*)d_in[3];
  const float* bi  = (const float*)d_in[4];
  const float* Whr = (const float*)d_in[5];
  const float* Whz = (const float*)d_in[6];
  const float* Whn = (const float*)d_in[7];
  const float* bhn = (const float*)d_in[8];
  float* out = (float*)d_out;

  char* ws = (char*)d_ws;
  __hip_bfloat16* gi = (__hip_bfloat16*)(ws + WS_GI);
  uint8_t* rst       = (uint8_t*)(ws + WS_RST);
  int* flag          = (int*)(ws + WS_FLAG);

  hipLaunchKernelGGL(detect_resets, dim3(1), dim3(256), 0, stream,
                     (const uint32_t*)rin, flag);
  hipLaunchKernelGGL(expand_resets, dim3(512), dim3(256), 0, stream, rin, flag, rst);
  hipLaunchKernelGGL(gi_gemm_mfma, dim3(256), dim3(1024), 0, stream, x, Wi, bi, gi);
  hipLaunchKernelGGL(gru_rec_mfma, dim3(4), dim3(1024), 0, stream, gi, rst, h0,
                     Whr, Whz, Whn, bhn, out);
}

// Round 3
// 5225.032 us; speedup vs baseline: 3.1366x; 1.4813x over previous
//
#include <hip/hip_runtime.h>
#include <hip/hip_bf16.h>
#include <cstdint>
#include <cstring>

#define T_DIM 2048
#define B_DIM 64
#define H_DIM 256
#define NSLOT 1024
#define NWG_REC 64
#define MAXLOC 2560

typedef __attribute__((ext_vector_type(8))) short bf16x8;
typedef __attribute__((ext_vector_type(4))) float f32x4;
typedef __attribute__((ext_vector_type(4))) short short4v;

// ---------------- ws layout (bytes) ----------------
static const size_t WS_GI      = 0;                       // 201326592  gi bf16 T*B*768
static const size_t WS_RST     = 201326592;               // 131072     resets u8
static const size_t WS_FLAG    = 201457664;               // 8          dtype flag
static const size_t WS_LIST    = 201457672;               // 1048576    seg list u64[131072]
static const size_t WS_ASSIGN  = 202506248;               // 524288     assign u32[131072]
static const size_t WS_WGSTEPS = 203030536;               // 256        u32[64]
static const size_t WS_TL      = 203030792;               // 10485760   timeline u32[NSLOT][MAXLOC]
// total ~213.5 MB

// timeline record bits: t:0-10, b:11-16, ACTIVE:17, START:18, HINIT:19, FINAL:20
#define RB_ACT   (1u << 17)
#define RB_START (1u << 18)
#define RB_HINIT (1u << 19)
#define RB_FINAL (1u << 20)

static __device__ __forceinline__ short f2bs(float f) {
  __hip_bfloat16 b = __float2bfloat16(f);
  short s; memcpy(&s, &b, 2); return s;
}
static __device__ __forceinline__ float bs2f(unsigned short u) {
  uint32_t v = ((uint32_t)u) << 16; float f; memcpy(&f, &v, 4); return f;
}
static __device__ __forceinline__ float sigm(float x) {
  return 1.f / (1.f + __expf(-x));
}
static __device__ __forceinline__ float tanh_fast(float x) {
  return 1.f - 2.f / (__expf(2.f * x) + 1.f);
}

// ---------------- resets dtype detection (verified R1/R2) ----------------
__global__ __launch_bounds__(256) void detect_resets(const uint32_t* __restrict__ rbuf,
                                                     int* __restrict__ flag_out) {
  __shared__ int v_u8, v_f32;
  if (threadIdx.x == 0) { v_u8 = 0; v_f32 = 0; }
  __syncthreads();
  int cu = 0, cf = 0;
  for (int i = threadIdx.x; i < 32768; i += 256) {
    uint32_t w = rbuf[i];
    if (w == 0x3F800000u) cf++;
    else if (w > 1u && (w & 0xFEFEFEFEu) == 0u) cu++;
  }
  atomicAdd(&v_u8, cu);
  atomicAdd(&v_f32, cf);
  __syncthreads();
  if (threadIdx.x == 0) *flag_out = (v_f32 > 0) ? 2 : ((v_u8 > 0) ? 1 : 0);
}

__global__ __launch_bounds__(256) void expand_resets(const void* __restrict__ rbuf,
                                                     const int* __restrict__ flag,
                                                     uint8_t* __restrict__ out) {
  int i = blockIdx.x * 256 + threadIdx.x;
  if (i >= T_DIM * B_DIM) return;
  int f = *flag;
  uint8_t v;
  if (f == 1)      v = (((const uint8_t*)rbuf)[i] != 0);
  else if (f == 2) v = (((const float*)rbuf)[i] != 0.f);
  else             v = (((const int*)rbuf)[i] != 0);
  out[i] = v;
}

// ---------------- gi = x @ Wi + bi via MFMA (verified R2) ----------------
__global__ __launch_bounds__(1024) void gi_gemm_mfma(const float* __restrict__ x,
                                                     const float* __restrict__ Wi,
                                                     const float* __restrict__ bi,
                                                     unsigned short* __restrict__ gi16) {
  __shared__ short hfrag[32 * 136];
  const int tid = threadIdx.x;
  const int lane = tid & 63, wave = tid >> 6;
  const int lq = lane >> 4, l15 = lane & 15;

  bf16x8 wfrag[3][8];
  const int colb = wave * 48 + l15;
#pragma unroll
  for (int nt = 0; nt < 3; ++nt) {
#pragma unroll
    for (int ks = 0; ks < 8; ++ks) {
      bf16x8 f;
#pragma unroll
      for (int e = 0; e < 8; ++e)
        f[e] = f2bs(Wi[(size_t)(ks * 32 + lq * 8 + e) * 768 + colb + nt * 16]);
      wfrag[nt][ks] = f;
    }
  }
  const float b0 = bi[colb], b1 = bi[colb + 16], b2 = bi[colb + 32];

  const int r = wave;
  const int kc = (tid & 63) * 4;
  const size_t m0 = (size_t)blockIdx.x * 32 * 16;

  float4 xv = *(const float4*)&x[(m0 + r) * 256 + kc];
  for (int i = 0; i < 32; ++i) {
    short4v xb = { f2bs(xv.x), f2bs(xv.y), f2bs(xv.z), f2bs(xv.w) };
    *(short4v*)&hfrag[(kc >> 3) * 136 + r * 8 + (kc & 7)] = xb;
    __syncthreads();
    if (i + 1 < 32)
      xv = *(const float4*)&x[(m0 + (size_t)(i + 1) * 16 + r) * 256 + kc];
    f32x4 c0 = {0.f,0.f,0.f,0.f}, c1 = {0.f,0.f,0.f,0.f}, c2 = {0.f,0.f,0.f,0.f};
#pragma unroll
    for (int ks = 0; ks < 8; ++ks) {
      bf16x8 a = *(const bf16x8*)&hfrag[(ks * 4 + lq) * 136 + l15 * 8];
      c0 = __builtin_amdgcn_mfma_f32_16x16x32_bf16(a, wfrag[0][ks], c0, 0, 0, 0);
      c1 = __builtin_amdgcn_mfma_f32_16x16x32_bf16(a, wfrag[1][ks], c1, 0, 0, 0);
      c2 = __builtin_amdgcn_mfma_f32_16x16x32_bf16(a, wfrag[2][ks], c2, 0, 0, 0);
    }
    __syncthreads();
    const size_t rowb = m0 + (size_t)i * 16;
#pragma unroll
    for (int qq = 0; qq < 4; ++qq) {
      const size_t row = rowb + lq * 4 + qq;
      gi16[row * 768 + colb]      = (unsigned short)f2bs(c0[qq] + b0);
      gi16[row * 768 + colb + 16] = (unsigned short)f2bs(c1[qq] + b1);
      gi16[row * 768 + colb + 32] = (unsigned short)f2bs(c2[qq] + b2);
    }
  }
}

// ---------------- zero the timeline ----------------
__global__ __launch_bounds__(1024) void zero_tl(uint32_t* __restrict__ tl) {
  tl[(size_t)blockIdx.x * 1024 + threadIdx.x] = 0;
}

// ---------------- build segment schedule ----------------
// Segments: [0,t1),[t1,t2),... per b, boundaries where rst=1 (h zeroed there).
// First segment uses h0 unless rst[0][b]. Greedy min-load assignment to
// NSLOT slots (slot = lane*16+q of wave 0), then fill per-slot timeline.
__global__ __launch_bounds__(1024) void build_schedule(const uint8_t* __restrict__ rst,
                                                       uint64_t* __restrict__ listG,
                                                       uint32_t* __restrict__ assignG,
                                                       uint32_t* __restrict__ wgsteps,
                                                       uint32_t* __restrict__ tl) {
  __shared__ uint32_t cnt[64];
  __shared__ uint32_t offs[65];
  __shared__ uint32_t nseg_s;
  const int tid = threadIdx.x;

  // pass 1: count segments per b
  if (tid < 64) {
    int b = tid, k = 1;
    for (int t = 1; t < 2048; ++t) k += rst[t * 64 + b];
    cnt[b] = k;
  }
  __syncthreads();
  if (tid == 0) {
    uint32_t a = 0;
    for (int b2 = 0; b2 < 64; ++b2) { offs[b2] = a; a += cnt[b2]; }
    offs[64] = a; nseg_s = a;
  }
  __syncthreads();
  // pass 2: emit segments.  u64: b:0-7 | hinit:8 | start:16-27 | len:32-47
  if (tid < 64) {
    int b = tid;
    uint32_t o = offs[b];
    int h0flag = rst[b] ? 0 : 1;
    int prev = 0;
    for (int t = 1; t < 2048; ++t) {
      if (rst[t * 64 + b]) {
        uint32_t hin = (prev == 0) ? (uint32_t)h0flag : 0u;
        listG[o++] = ((uint64_t)(uint32_t)(t - prev) << 32) |
                     ((uint32_t)prev << 16) | (hin << 8) | (uint32_t)b;
        prev = t;
      }
    }
    uint32_t hin = (prev == 0) ? (uint32_t)h0flag : 0u;
    listG[o++] = ((uint64_t)(uint32_t)(2048 - prev) << 32) |
                 ((uint32_t)prev << 16) | (hin << 8) | (uint32_t)b;
  }
  __syncthreads();
  const uint32_t NSEG = nseg_s;

  // greedy min-load assignment (wave 0; lane holds loads of slots lane*16+q)
  if (tid < 64) {
    uint32_t ld[16];
#pragma unroll
    for (int q = 0; q < 16; ++q) ld[q] = 0;
    for (uint32_t s0 = 0; s0 < NSEG; s0 += 64) {
      unsigned long long myseg = (s0 + (uint32_t)tid < NSEG)
                                   ? (unsigned long long)listG[s0 + tid] : 0ull;
      for (int j = 0; j < 64; ++j) {
        if (s0 + (uint32_t)j >= NSEG) break;
        unsigned long long sj = __shfl(myseg, j, 64);
        uint32_t len = (uint32_t)(sj >> 32) & 0xFFFFu;
        if (len == 0) continue;
        uint32_t best = 0xFFFFFFFFu;
#pragma unroll
        for (int q = 0; q < 16; ++q) {
          uint32_t cand = (ld[q] << 10) | ((uint32_t)tid << 4) | (uint32_t)q;
          best = best < cand ? best : cand;
        }
#pragma unroll
        for (int d = 1; d < 64; d <<= 1) {
          uint32_t ob = __shfl_xor(best, d, 64);
          best = best < ob ? best : ob;
        }
        uint32_t wlane = (best >> 4) & 63u, wq = best & 15u, ofs = best >> 10;
        if (tid == (int)wlane) {
#pragma unroll
          for (int q = 0; q < 16; ++q) if ((uint32_t)q == wq) ld[q] += len;
          assignG[s0 + j] = (wlane * 16 + wq) | (ofs << 10);
        }
      }
    }
    uint32_t mx = 0;
#pragma unroll
    for (int q = 0; q < 16; ++q) mx = mx > ld[q] ? mx : ld[q];
    wgsteps[tid] = mx;
  }
  __syncthreads();

  // fill timeline: tl[slot*MAXLOC + ofs + i]
  for (uint32_t s = tid; s < NSEG; s += 1024) {
    uint64_t sg = listG[s];
    uint32_t a = assignG[s];
    uint32_t slot = a & 1023u, ofs = a >> 10;
    uint32_t b = (uint32_t)sg & 63u;
    uint32_t hinit = ((uint32_t)sg >> 8) & 1u;
    uint32_t start = ((uint32_t)sg >> 16) & 0xFFFu;
    uint32_t len = (uint32_t)(sg >> 32) & 0xFFFFu;
    uint32_t endt = start + len;
    for (uint32_t i = 0; i < len; ++i) {
      uint32_t rec = (start + i) | (b << 11) | RB_ACT;
      if (i == 0) rec |= RB_START | (hinit << 19);
      if (i == len - 1 && endt == 2048) rec |= RB_FINAL;
      tl[(size_t)slot * MAXLOC + ofs + i] = rec;
    }
  }
}

// ---------------- segment-parallel GRU recurrence ----------------
// 64 WGs x 16 waves. WG owns slots [wg*16, wg*16+16) = MFMA rows 0..15.
// Wave w owns h-cols w*16..w*16+15; B-frags of Whr/Whz/Whn for those cols
// resident in registers -> C frags are (r,z,n) sums for exactly the lane's
// columns: pointwise fully in-register, one barrier/step.
__global__ __launch_bounds__(1024) void gru_rec_seg(const unsigned short* __restrict__ gi16,
                                                    const float* __restrict__ h0,
                                                    const float* __restrict__ Whr,
                                                    const float* __restrict__ Whz,
                                                    const float* __restrict__ Whn,
                                                    const float* __restrict__ bhn,
                                                    const uint32_t* __restrict__ tl,
                                                    const uint32_t* __restrict__ wgsteps,
                                                    float* __restrict__ out) {
  __shared__ short hfrag[2][32 * 136];
  const int tid = threadIdx.x;
  const int lane = tid & 63, wave = tid >> 6;
  const int lq = lane >> 4, l15 = lane & 15;
  const int col = wave * 16 + l15;
  const int slotbase = blockIdx.x * 16;

  // resident weight fragments: gate g cols = col
  bf16x8 wfrag[3][8];
#pragma unroll
  for (int nt = 0; nt < 3; ++nt) {
    const float* W = (nt == 0) ? Whr : ((nt == 1) ? Whz : Whn);
#pragma unroll
    for (int ks = 0; ks < 8; ++ks) {
      bf16x8 f;
#pragma unroll
      for (int e = 0; e < 8; ++e)
        f[e] = f2bs(W[(size_t)(ks * 32 + lq * 8 + e) * 256 + col]);
      wfrag[nt][ks] = f;
    }
  }
  const float bn = bhn[col];
  const int nsteps = (int)wgsteps[blockIdx.x];

  // record + gi prefetch pipelines (rows lq*4+qq)
  uint32_t R0[4], R1[4];
  unsigned short G0[12];
  float hreg[4];
#pragma unroll
  for (int qq = 0; qq < 4; ++qq) {
    R0[qq] = tl[(size_t)(slotbase + lq * 4 + qq) * MAXLOC + 0];
    R1[qq] = tl[(size_t)(slotbase + lq * 4 + qq) * MAXLOC + 1];
  }
#pragma unroll
  for (int qq = 0; qq < 4; ++qq) {
    uint32_t r = R0[qq];
    size_t gb = ((size_t)(r & 0x7FFu) * 64 + ((r >> 11) & 63u)) * 768 + col;
    G0[qq * 3 + 0] = gi16[gb];
    G0[qq * 3 + 1] = gi16[gb + 256];
    G0[qq * 3 + 2] = gi16[gb + 512];
  }
#pragma unroll
  for (int qq = 0; qq < 4; ++qq) {
    uint32_t r = R0[qq];
    float hv = 0.f;
    if ((r & RB_ACT) && (r & RB_START) && (r & RB_HINIT))
      hv = h0[(size_t)((r >> 11) & 63u) * 256 + col];
    hreg[qq] = hv;
    hfrag[0][(col >> 3) * 136 + (lq * 4 + qq) * 8 + (col & 7)] = f2bs(hv);
  }
  __syncthreads();

  int cur = 0;
  for (int i = 0; i < nsteps; ++i) {
    // prefetch records for i+2 and gi for i+1
    uint32_t R2[4];
    unsigned short G1[12];
#pragma unroll
    for (int qq = 0; qq < 4; ++qq)
      R2[qq] = tl[(size_t)(slotbase + lq * 4 + qq) * MAXLOC + i + 2];
#pragma unroll
    for (int qq = 0; qq < 4; ++qq) {
      uint32_t r = R1[qq];
      size_t gb = ((size_t)(r & 0x7FFu) * 64 + ((r >> 11) & 63u)) * 768 + col;
      G1[qq * 3 + 0] = gi16[gb];
      G1[qq * 3 + 1] = gi16[gb + 256];
      G1[qq * 3 + 2] = gi16[gb + 512];
    }

    // S = h @ [Whr|Whz|Whn] restricted to this wave's 16 columns
    f32x4 c0 = {0.f,0.f,0.f,0.f}, c1 = {0.f,0.f,0.f,0.f}, c2 = {0.f,0.f,0.f,0.f};
#pragma unroll
    for (int ks = 0; ks < 8; ++ks) {
      bf16x8 a = *(const bf16x8*)&hfrag[cur][(ks * 4 + lq) * 136 + l15 * 8];
      c0 = __builtin_amdgcn_mfma_f32_16x16x32_bf16(a, wfrag[0][ks], c0, 0, 0, 0);
      c1 = __builtin_amdgcn_mfma_f32_16x16x32_bf16(a, wfrag[1][ks], c1, 0, 0, 0);
      c2 = __builtin_amdgcn_mfma_f32_16x16x32_bf16(a, wfrag[2][ks], c2, 0, 0, 0);
    }

    // pointwise + output + next-h
#pragma unroll
    for (int qq = 0; qq < 4; ++qq) {
      uint32_t r0 = R0[qq];
      float gr = bs2f(G0[qq * 3 + 0]);
      float gz = bs2f(G0[qq * 3 + 1]);
      float gn = bs2f(G0[qq * 3 + 2]);
      float rr = sigm(gr + c0[qq]);
      float zz = sigm(gz + c1[qq]);
      float nn = tanh_fast(gn + rr * (c2[qq] + bn));
      float hn_ = (1.f - zz) * nn + zz * hreg[qq];
      if (r0 & RB_ACT) {
        uint32_t t = r0 & 0x7FFu, b = (r0 >> 11) & 63u;
        out[16384 + ((size_t)t * 64 + b) * 256 + col] = hn_;
        if (r0 & RB_FINAL) out[(size_t)b * 256 + col] = hn_;
      }
      uint32_t r1 = R1[qq];
      float hnext;
      if (!(r1 & RB_ACT)) hnext = 0.f;
      else if (r1 & RB_START)
        hnext = (r1 & RB_HINIT) ? h0[(size_t)((r1 >> 11) & 63u) * 256 + col] : 0.f;
      else hnext = hn_;
      hreg[qq] = hnext;
      hfrag[cur ^ 1][(col >> 3) * 136 + (lq * 4 + qq) * 8 + (col & 7)] = f2bs(hnext);
      R0[qq] = r1; R1[qq] = R2[qq];
      G0[qq * 3 + 0] = G1[qq * 3 + 0];
      G0[qq * 3 + 1] = G1[qq * 3 + 1];
      G0[qq * 3 + 2] = G1[qq * 3 + 2];
    }
    cur ^= 1;
    __syncthreads();
  }
}

extern "C" void kernel_launch(void* const* d_in, const int* in_sizes, int n_in,
                              void* d_out, int out_size, void* d_ws, size_t ws_size,
                              hipStream_t stream) {
  const float* x   = (const float*)d_in[0];
  const void*  rin = d_in[1];
  const float* h0  = (const float*)d_in[2];
  const float* Wi  = (const float*)d_in[3];
  const float* bi  = (const float*)d_in[4];
  const float* Whr = (const float*)d_in[5];
  const float* Whz = (const float*)d_in[6];
  const float* Whn = (const float*)d_in[7];
  const float* bhn = (const float*)d_in[8];
  float* out = (float*)d_out;

  char* ws = (char*)d_ws;
  unsigned short* gi = (unsigned short*)(ws + WS_GI);
  uint8_t* rst       = (uint8_t*)(ws + WS_RST);
  int* flag          = (int*)(ws + WS_FLAG);
  uint64_t* listG    = (uint64_t*)(ws + WS_LIST);
  uint32_t* assignG  = (uint32_t*)(ws + WS_ASSIGN);
  uint32_t* wgsteps  = (uint32_t*)(ws + WS_WGSTEPS);
  uint32_t* tl       = (uint32_t*)(ws + WS_TL);

  hipLaunchKernelGGL(detect_resets, dim3(1), dim3(256), 0, stream,
                     (const uint32_t*)rin, flag);
  hipLaunchKernelGGL(expand_resets, dim3(512), dim3(256), 0, stream, rin, flag, rst);
  hipLaunchKernelGGL(zero_tl, dim3(MAXLOC), dim3(1024), 0, stream, tl);
  hipLaunchKernelGGL(build_schedule, dim3(1), dim3(1024), 0, stream,
                     rst, listG, assignG, wgsteps, tl);
  hipLaunchKernelGGL(gi_gemm_mfma, dim3(256), dim3(1024), 0, stream, x, Wi, bi, gi);
  hipLaunchKernelGGL(gru_rec_seg, dim3(NWG_REC), dim3(1024), 0, stream,
                     gi, h0, Whr, Whz, Whn, bhn, tl, wgsteps, out);
}

// Round 4
// 2926.859 us; speedup vs baseline: 5.5994x; 1.7852x over previous
//
#include <hip/hip_runtime.h>
#include <hip/hip_bf16.h>
#include <cstdint>
#include <cstring>

#define T_DIM 2048
#define B_DIM 64
#define H_DIM 256
#define NSLOT 1024
#define NWG_REC 64
#define MAXLOC 2560
#define HSTRIDE 264   // shorts; 528B rows -> 16B-aligned, spreads bank groups

typedef __attribute__((ext_vector_type(8))) short bf16x8;
typedef __attribute__((ext_vector_type(4))) float f32x4;
typedef __attribute__((ext_vector_type(4))) short short4v;

// ---------------- ws layout (bytes) ----------------
static const size_t WS_GI      = 0;                       // 201326592  gi bf16 T*B*768
static const size_t WS_RST     = 201326592;               // 131072     resets u8
static const size_t WS_FLAG    = 201457664;               // 8          dtype flag
static const size_t WS_LIST    = 201457672;               // 1048576    seg list u64 (max 131072 segs)
static const size_t WS_ASSIGN  = 202506248;               // 524288     per-seg ofs u32
static const size_t WS_WGSTEPS = 203030536;               // 256        u32[64]
static const size_t WS_TL      = 203030792;               // 10485760   timeline u32[NSLOT][MAXLOC]
// total ~213.5 MB (same footprint as R3, proven)

// timeline record bits: t:0-10, b:11-16, ACTIVE:17, START:18, HINIT:19, FINAL:20
#define RB_ACT   (1u << 17)
#define RB_START (1u << 18)
#define RB_HINIT (1u << 19)
#define RB_FINAL (1u << 20)

static __device__ __forceinline__ short f2bs(float f) {
  __hip_bfloat16 b = __float2bfloat16(f);
  short s; memcpy(&s, &b, 2); return s;
}
static __device__ __forceinline__ float bs2f(unsigned short u) {
  uint32_t v = ((uint32_t)u) << 16; float f; memcpy(&f, &v, 4); return f;
}
static __device__ __forceinline__ float sigm(float x) {
  return 1.f / (1.f + __expf(-x));
}
static __device__ __forceinline__ float tanh_fast(float x) {
  return 1.f - 2.f / (__expf(2.f * x) + 1.f);
}

// ---------------- resets dtype detection (verified R1-R3) ----------------
__global__ __launch_bounds__(256) void detect_resets(const uint32_t* __restrict__ rbuf,
                                                     int* __restrict__ flag_out) {
  __shared__ int v_u8, v_f32;
  if (threadIdx.x == 0) { v_u8 = 0; v_f32 = 0; }
  __syncthreads();
  int cu = 0, cf = 0;
  for (int i = threadIdx.x; i < 32768; i += 256) {
    uint32_t w = rbuf[i];
    if (w == 0x3F800000u) cf++;
    else if (w > 1u && (w & 0xFEFEFEFEu) == 0u) cu++;
  }
  atomicAdd(&v_u8, cu);
  atomicAdd(&v_f32, cf);
  __syncthreads();
  if (threadIdx.x == 0) *flag_out = (v_f32 > 0) ? 2 : ((v_u8 > 0) ? 1 : 0);
}

__global__ __launch_bounds__(256) void expand_resets(const void* __restrict__ rbuf,
                                                     const int* __restrict__ flag,
                                                     uint8_t* __restrict__ out) {
  int i = blockIdx.x * 256 + threadIdx.x;
  if (i >= T_DIM * B_DIM) return;
  int f = *flag;
  uint8_t v;
  if (f == 1)      v = (((const uint8_t*)rbuf)[i] != 0);
  else if (f == 2) v = (((const float*)rbuf)[i] != 0.f);
  else             v = (((const int*)rbuf)[i] != 0);
  out[i] = v;
}

// ---------------- gi = x @ Wi + bi via MFMA (verified R2/R3) ----------------
__global__ __launch_bounds__(1024) void gi_gemm_mfma(const float* __restrict__ x,
                                                     const float* __restrict__ Wi,
                                                     const float* __restrict__ bi,
                                                     unsigned short* __restrict__ gi16) {
  __shared__ short hfrag[32 * 136];
  const int tid = threadIdx.x;
  const int lane = tid & 63, wave = tid >> 6;
  const int lq = lane >> 4, l15 = lane & 15;

  bf16x8 wfrag[3][8];
  const int colb = wave * 48 + l15;
#pragma unroll
  for (int nt = 0; nt < 3; ++nt) {
#pragma unroll
    for (int ks = 0; ks < 8; ++ks) {
      bf16x8 f;
#pragma unroll
      for (int e = 0; e < 8; ++e)
        f[e] = f2bs(Wi[(size_t)(ks * 32 + lq * 8 + e) * 768 + colb + nt * 16]);
      wfrag[nt][ks] = f;
    }
  }
  const float b0 = bi[colb], b1 = bi[colb + 16], b2 = bi[colb + 32];

  const int r = wave;
  const int kc = (tid & 63) * 4;
  const size_t m0 = (size_t)blockIdx.x * 32 * 16;

  float4 xv = *(const float4*)&x[(m0 + r) * 256 + kc];
  for (int i = 0; i < 32; ++i) {
    short4v xb = { f2bs(xv.x), f2bs(xv.y), f2bs(xv.z), f2bs(xv.w) };
    *(short4v*)&hfrag[(kc >> 3) * 136 + r * 8 + (kc & 7)] = xb;
    __syncthreads();
    if (i + 1 < 32)
      xv = *(const float4*)&x[(m0 + (size_t)(i + 1) * 16 + r) * 256 + kc];
    f32x4 c0 = {0.f,0.f,0.f,0.f}, c1 = {0.f,0.f,0.f,0.f}, c2 = {0.f,0.f,0.f,0.f};
#pragma unroll
    for (int ks = 0; ks < 8; ++ks) {
      bf16x8 a = *(const bf16x8*)&hfrag[(ks * 4 + lq) * 136 + l15 * 8];
      c0 = __builtin_amdgcn_mfma_f32_16x16x32_bf16(a, wfrag[0][ks], c0, 0, 0, 0);
      c1 = __builtin_amdgcn_mfma_f32_16x16x32_bf16(a, wfrag[1][ks], c1, 0, 0, 0);
      c2 = __builtin_amdgcn_mfma_f32_16x16x32_bf16(a, wfrag[2][ks], c2, 0, 0, 0);
    }
    __syncthreads();
    const size_t rowb = m0 + (size_t)i * 16;
#pragma unroll
    for (int qq = 0; qq < 4; ++qq) {
      const size_t row = rowb + lq * 4 + qq;
      gi16[row * 768 + colb]      = (unsigned short)f2bs(c0[qq] + b0);
      gi16[row * 768 + colb + 16] = (unsigned short)f2bs(c1[qq] + b1);
      gi16[row * 768 + colb + 32] = (unsigned short)f2bs(c2[qq] + b2);
    }
  }
}

// ---------------- zero the timeline ----------------
__global__ __launch_bounds__(1024) void zero_tl(uint32_t* __restrict__ tl) {
  tl[(size_t)blockIdx.x * 1024 + threadIdx.x] = 0;
}

// ---------------- build segment schedule (parallel, no greedy) ----------------
// Segment s -> slot s % 1024; slot q*64+wg belongs to WG wg (declusters
// consecutive same-b segments across WGs). Offsets within slot via LDS atomics.
__global__ __launch_bounds__(256) void build_schedule(const uint8_t* __restrict__ rst,
                                                      uint64_t* __restrict__ listG,
                                                      uint32_t* __restrict__ assignG,
                                                      uint32_t* __restrict__ wgsteps,
                                                      uint32_t* __restrict__ tl) {
  __shared__ uint32_t slotload[NSLOT];
  __shared__ uint32_t cnt[64];
  __shared__ uint32_t offs[65];
  __shared__ uint32_t nseg_s;
  const int tid = threadIdx.x;

  for (int i = tid; i < NSLOT; i += 256) slotload[i] = 0;
  __syncthreads();

  // pass 1: count segments per b
  if (tid < 64) {
    int b = tid, k = 1;
    for (int t = 1; t < 2048; ++t) k += rst[t * 64 + b];
    cnt[b] = k;
  }
  __syncthreads();
  if (tid == 0) {
    uint32_t a = 0;
    for (int b2 = 0; b2 < 64; ++b2) { offs[b2] = a; a += cnt[b2]; }
    offs[64] = a; nseg_s = a;
  }
  __syncthreads();
  // pass 2: emit segments.  u64: b:0-7 | hinit:8 | start:16-27 | len:32-47
  if (tid < 64) {
    int b = tid;
    uint32_t o = offs[b];
    int h0flag = rst[b] ? 0 : 1;
    int prev = 0;
    for (int t = 1; t < 2048; ++t) {
      if (rst[t * 64 + b]) {
        uint32_t hin = (prev == 0) ? (uint32_t)h0flag : 0u;
        listG[o++] = ((uint64_t)(uint32_t)(t - prev) << 32) |
                     ((uint32_t)prev << 16) | (hin << 8) | (uint32_t)b;
        prev = t;
      }
    }
    uint32_t hin = (prev == 0) ? (uint32_t)h0flag : 0u;
    listG[o++] = ((uint64_t)(uint32_t)(2048 - prev) << 32) |
                 ((uint32_t)prev << 16) | (hin << 8) | (uint32_t)b;
  }
  __syncthreads();
  const uint32_t NSEG = nseg_s;

  // placement: slot = s % NSLOT, ofs = atomic fetch-add on slot load
  for (uint32_t s = tid; s < NSEG; s += 256) {
    uint32_t len = (uint32_t)(listG[s] >> 32) & 0xFFFFu;
    uint32_t slot = s & (NSLOT - 1);
    assignG[s] = atomicAdd(&slotload[slot], len);
  }
  __syncthreads();

  // per-WG step count = max load over its 16 slots (slot = q*64 + wg)
  if (tid < 64) {
    uint32_t mx = 0;
#pragma unroll
    for (int q = 0; q < 16; ++q) {
      uint32_t v = slotload[q * 64 + tid];
      mx = mx > v ? mx : v;
    }
    wgsteps[tid] = mx < MAXLOC ? mx : MAXLOC;
  }

  // fill timeline
  for (uint32_t s = tid; s < NSEG; s += 256) {
    uint64_t sg = listG[s];
    uint32_t slot = s & (NSLOT - 1);
    uint32_t ofs = assignG[s];
    uint32_t b = (uint32_t)sg & 63u;
    uint32_t hinit = ((uint32_t)sg >> 8) & 1u;
    uint32_t start = ((uint32_t)sg >> 16) & 0xFFFu;
    uint32_t len = (uint32_t)(sg >> 32) & 0xFFFFu;
    uint32_t endt = start + len;
    for (uint32_t i = 0; i < len; ++i) {
      if (ofs + i >= MAXLOC) break;  // astronomically rare clamp
      uint32_t rec = (start + i) | (b << 11) | RB_ACT;
      if (i == 0) rec |= RB_START | (hinit << 19);
      if (i == len - 1 && endt == 2048) rec |= RB_FINAL;
      tl[(size_t)slot * MAXLOC + ofs + i] = rec;
    }
  }
}

// ---------------- segment-parallel GRU recurrence (transposed MFMA) ----------------
// 64 WGs x 16 waves. Slot of MFMA-col l15 = l15*64 + wg. Wave w owns h-cols
// [w*16, w*16+16). C = W^T (A-op) x h^T (B-op): thread (w,lq,l15) gets gate
// values for slot l15, cols w*16+lq*4..+3 -> fully vectorized pointwise:
// gi 3x ushort4, h-writeback 1x ds_write_b64, out 1x float4, 1 record/thread.
// Wr,Wz fragments resident in VGPR; Wn^T staged in LDS (col-major, 132KB).
__global__ __launch_bounds__(1024) void gru_rec_seg(const unsigned short* __restrict__ gi16,
                                                    const float* __restrict__ h0,
                                                    const float* __restrict__ Whr,
                                                    const float* __restrict__ Whz,
                                                    const float* __restrict__ Whn,
                                                    const float* __restrict__ bhn,
                                                    const uint32_t* __restrict__ tl,
                                                    const uint32_t* __restrict__ wgsteps,
                                                    float* __restrict__ out) {
  __shared__ short wn_lds[256 * HSTRIDE];     // Wn^T: [col][k], 132KB
  __shared__ short hfrag[2][16 * HSTRIDE];    // h^T-ready: [slot][hcol], 2x8.25KB
  const int tid = threadIdx.x;
  const int lane = tid & 63, w = tid >> 6;
  const int lq = lane >> 4, l15 = lane & 15;
  const int wg = blockIdx.x;

  // resident Wr/Wz A-fragments: lane (lq,l15) holds W[k=ks*32+lq*8+e][w*16+l15]
  bf16x8 wfragR[8], wfragZ[8];
  {
    const int wcol = w * 16 + l15;
#pragma unroll
    for (int ks = 0; ks < 8; ++ks) {
      bf16x8 fr, fz;
#pragma unroll
      for (int e = 0; e < 8; ++e) {
        fr[e] = f2bs(Whr[(size_t)(ks * 32 + lq * 8 + e) * 256 + wcol]);
        fz[e] = f2bs(Whz[(size_t)(ks * 32 + lq * 8 + e) * 256 + wcol]);
      }
      wfragR[ks] = fr; wfragZ[ks] = fz;
    }
  }

  // stage Wn^T into LDS col-major: wn_lds[col*HSTRIDE + k]
  {
    const int col = tid & 255, kb = (tid >> 8) * 64;
    for (int kk = 0; kk < 64; kk += 4) {
      short4v v;
#pragma unroll
      for (int u = 0; u < 4; ++u)
        v[u] = f2bs(Whn[(size_t)(kb + kk + u) * 256 + col]);
      *(short4v*)&wn_lds[col * HSTRIDE + kb + kk] = v;
    }
  }

  const int col0 = w * 16 + lq * 4;           // this thread's 4 output cols
  const float4 bnv = *(const float4*)&bhn[col0];
  const int nsteps = (int)wgsteps[wg];
  const uint32_t* tlb = tl + (size_t)(l15 * 64 + wg) * MAXLOC;

  // pipelines: records depth-2, gi depth-1
  uint32_t R0 = tlb[0], R1 = tlb[1];
  ushort4 G0a, G0b, G0c;
  {
    size_t gb = ((size_t)(R0 & 0x7FFu) * 64 + ((R0 >> 11) & 63u)) * 768 + col0;
    G0a = *(const ushort4*)&gi16[gb];
    G0b = *(const ushort4*)&gi16[gb + 256];
    G0c = *(const ushort4*)&gi16[gb + 512];
  }
  float hreg[4];
  {
    float4 hv = {0.f, 0.f, 0.f, 0.f};
    if ((R0 & RB_ACT) && (R0 & RB_START) && (R0 & RB_HINIT))
      hv = *(const float4*)&h0[(size_t)((R0 >> 11) & 63u) * 256 + col0];
    hreg[0] = hv.x; hreg[1] = hv.y; hreg[2] = hv.z; hreg[3] = hv.w;
    short4v hb = { f2bs(hv.x), f2bs(hv.y), f2bs(hv.z), f2bs(hv.w) };
    *(short4v*)&hfrag[0][l15 * HSTRIDE + col0] = hb;
  }
  __syncthreads();

  int cur = 0;
  for (int i = 0; i < nsteps; ++i) {
    // prefetch record i+2 and gi for step i+1
    uint32_t R2 = tlb[i + 2];
    ushort4 G1a, G1b, G1c;
    {
      size_t gb = ((size_t)(R1 & 0x7FFu) * 64 + ((R1 >> 11) & 63u)) * 768 + col0;
      G1a = *(const ushort4*)&gi16[gb];
      G1b = *(const ushort4*)&gi16[gb + 256];
      G1c = *(const ushort4*)&gi16[gb + 512];
    }

    // C[gate][wcol][slot] = W^T x h^T
    f32x4 c0 = {0.f,0.f,0.f,0.f}, c1 = {0.f,0.f,0.f,0.f}, c2 = {0.f,0.f,0.f,0.f};
    const short* hbase = &hfrag[cur][l15 * HSTRIDE + lq * 8];
    const short* wnbase = &wn_lds[(w * 16 + l15) * HSTRIDE + lq * 8];
#pragma unroll
    for (int ks = 0; ks < 8; ++ks) {
      bf16x8 hv = *(const bf16x8*)&hbase[ks * 32];
      bf16x8 wv = *(const bf16x8*)&wnbase[ks * 32];
      c0 = __builtin_amdgcn_mfma_f32_16x16x32_bf16(wfragR[ks], hv, c0, 0, 0, 0);
      c1 = __builtin_amdgcn_mfma_f32_16x16x32_bf16(wfragZ[ks], hv, c1, 0, 0, 0);
      c2 = __builtin_amdgcn_mfma_f32_16x16x32_bf16(wv, hv, c2, 0, 0, 0);
    }

    // pointwise for slot l15, cols col0..col0+3
    const unsigned short* g0 = (const unsigned short*)&G0a;
    const unsigned short* g1 = (const unsigned short*)&G0b;
    const unsigned short* g2 = (const unsigned short*)&G0c;
    float hn_[4];
#pragma unroll
    for (int qq = 0; qq < 4; ++qq) {
      float rr = sigm(bs2f(g0[qq]) + c0[qq]);
      float zz = sigm(bs2f(g1[qq]) + c1[qq]);
      float bn = (qq == 0) ? bnv.x : (qq == 1) ? bnv.y : (qq == 2) ? bnv.z : bnv.w;
      float nn = tanh_fast(bs2f(g2[qq]) + rr * (c2[qq] + bn));
      hn_[qq] = (1.f - zz) * nn + zz * hreg[qq];
    }
    if (R0 & RB_ACT) {
      uint32_t t = R0 & 0x7FFu, b = (R0 >> 11) & 63u;
      float4 ho = { hn_[0], hn_[1], hn_[2], hn_[3] };
      *(float4*)&out[16384 + ((size_t)t * 64 + b) * 256 + col0] = ho;
      if (R0 & RB_FINAL)
        *(float4*)&out[(size_t)b * 256 + col0] = ho;
    }

    // next h: segment boundaries
    float4 hx = { hn_[0], hn_[1], hn_[2], hn_[3] };
    if (!(R1 & RB_ACT)) {
      hx.x = hx.y = hx.z = hx.w = 0.f;
    } else if (R1 & RB_START) {
      if (R1 & RB_HINIT)
        hx = *(const float4*)&h0[(size_t)((R1 >> 11) & 63u) * 256 + col0];
      else { hx.x = hx.y = hx.z = hx.w = 0.f; }
    }
    hreg[0] = hx.x; hreg[1] = hx.y; hreg[2] = hx.z; hreg[3] = hx.w;
    short4v hb = { f2bs(hx.x), f2bs(hx.y), f2bs(hx.z), f2bs(hx.w) };
    *(short4v*)&hfrag[cur ^ 1][l15 * HSTRIDE + col0] = hb;

    R0 = R1; R1 = R2;
    G0a = G1a; G0b = G1b; G0c = G1c;
    cur ^= 1;
    __syncthreads();
  }
}

extern "C" void kernel_launch(void* const* d_in, const int* in_sizes, int n_in,
                              void* d_out, int out_size, void* d_ws, size_t ws_size,
                              hipStream_t stream) {
  const float* x   = (const float*)d_in[0];
  const void*  rin = d_in[1];
  const float* h0  = (const float*)d_in[2];
  const float* Wi  = (const float*)d_in[3];
  const float* bi  = (const float*)d_in[4];
  const float* Whr = (const float*)d_in[5];
  const float* Whz = (const float*)d_in[6];
  const float* Whn = (const float*)d_in[7];
  const float* bhn = (const float*)d_in[8];
  float* out = (float*)d_out;

  char* ws = (char*)d_ws;
  unsigned short* gi = (unsigned short*)(ws + WS_GI);
  uint8_t* rst       = (uint8_t*)(ws + WS_RST);
  int* flag          = (int*)(ws + WS_FLAG);
  uint64_t* listG    = (uint64_t*)(ws + WS_LIST);
  uint32_t* assignG  = (uint32_t*)(ws + WS_ASSIGN);
  uint32_t* wgsteps  = (uint32_t*)(ws + WS_WGSTEPS);
  uint32_t* tl       = (uint32_t*)(ws + WS_TL);

  hipLaunchKernelGGL(detect_resets, dim3(1), dim3(256), 0, stream,
                     (const uint32_t*)rin, flag);
  hipLaunchKernelGGL(expand_resets, dim3(512), dim3(256), 0, stream, rin, flag, rst);
  hipLaunchKernelGGL(zero_tl, dim3(MAXLOC), dim3(1024), 0, stream, tl);
  hipLaunchKernelGGL(build_schedule, dim3(1), dim3(256), 0, stream,
                     rst, listG, assignG, wgsteps, tl);
  hipLaunchKernelGGL(gi_gemm_mfma, dim3(256), dim3(1024), 0, stream, x, Wi, bi, gi);
  hipLaunchKernelGGL(gru_rec_seg, dim3(NWG_REC), dim3(1024), 0, stream,
                     gi, h0, Whr, Whz, Whn, bhn, tl, wgsteps, out);
}